// Round 10
// baseline (180.033 us; speedup 1.0000x reference)
//
#include <hip/hip_runtime.h>

#define NPOS 21824          // 16384+4096+1024+256+64 positions per image
#define MINS 0.05f
#define BT2  256            // threads per block
#define NW2  4              // waves per block
#define TFAST 0.85f         // static pre-filter threshold (fast path only)
#define SEC  8              // sectors per image (s = blk & 7)
#define SCAP 2048           // per-sector list region capacity
#define CAP  (SEC*SCAP)     // per-image list capacity (fixed regions)
#define CSTRIDE 32          // counter padding: 32 ints = 128 B

struct Ptrs { const float* cls[5]; const float* reg[5]; const float* ctr[5]; };

__device__ __forceinline__ float sigf(float x){ return 1.0f/(1.0f+expf(-x)); }

// ---- per-access agent coherence (multi-XCD safe, NO buffer_wbl2 fences) ----
__device__ __forceinline__ void cstore_u32(unsigned* p, unsigned v){
    __hip_atomic_store(p, v, __ATOMIC_RELAXED, __HIP_MEMORY_SCOPE_AGENT);
}
__device__ __forceinline__ void cstore_i32(int* p, int v){
    __hip_atomic_store(p, v, __ATOMIC_RELAXED, __HIP_MEMORY_SCOPE_AGENT);
}
__device__ __forceinline__ void cstore_u64(unsigned long long* p, unsigned long long v){
    __hip_atomic_store(p, v, __ATOMIC_RELAXED, __HIP_MEMORY_SCOPE_AGENT);
}
__device__ __forceinline__ unsigned cload_u32(const unsigned* p){
    return __hip_atomic_load(p, __ATOMIC_RELAXED, __HIP_MEMORY_SCOPE_AGENT);
}
__device__ __forceinline__ int cload_i32(const int* p){
    return __hip_atomic_load(p, __ATOMIC_RELAXED, __HIP_MEMORY_SCOPE_AGENT);
}
__device__ __forceinline__ unsigned long long cload_u64(const unsigned long long* p){
    return __hip_atomic_load(p, __ATOMIC_RELAXED, __HIP_MEMORY_SCOPE_AGENT);
}

// key = (score_bits<<16) | (65535-p): desc key == desc score, ties lower p.
__device__ __forceinline__ unsigned long long mkkey(unsigned int b, int p){
    return ((unsigned long long)b << 16) | (unsigned)(65535 - p);
}

// Recompute the snapped box for position p (bit-identical to the original
// k_score path). reg is an input tensor — normal loads are fine.
__device__ __forceinline__ float4 computeBox(const Ptrs& P, int img, int p){
    int base, lw, stride, lvl;
    if (p < 16384)      { lvl=0; base=0;     lw=7; stride=8;   }
    else if (p < 20480) { lvl=1; base=16384; lw=6; stride=16;  }
    else if (p < 21504) { lvl=2; base=20480; lw=5; stride=32;  }
    else if (p < 21760) { lvl=3; base=21504; lw=4; stride=64;  }
    else                { lvl=4; base=21760; lw=3; stride=128; }
    int pl = p - base;
    int h = pl >> lw, w = pl & ((1<<lw)-1);
    long long lidx = (long long)img*(1<<(2*lw)) + pl;
    float4 rg = ((const float4*)P.reg[lvl])[lidx];
    float x = (w + 0.5f)*(float)stride;
    float y = (h + 0.5f)*(float)stride;
    int ix1 = (int)(x - expf(rg.x));
    int iy1 = (int)(y - expf(rg.y));
    int ix2 = (int)(x + expf(rg.z));
    int iy2 = (int)(y + expf(rg.w));
    ix1 = max(ix1,0); iy1 = max(iy1,0);
    ix2 = min(ix2,1023); iy2 = min(iy2,1023);
    return make_float4((float)ix1,(float)iy1,(float)ix2,(float)iy2);
}

// ---- suffix-scan pick over a 2048-bin LDS histogram (8 bins/thread) --------
__device__ void suffix_pick(const int* hist, int* wsum, int K,
                            unsigned int prefBase, int shift,
                            unsigned int* shPref, int* shK, int tid)
{
    const int g = 2048 / BT2;        // 8 bins per thread
    int lo = tid*g, ls = 0;
#pragma unroll
    for (int q = 0; q < g; ++q) ls += hist[lo + q];
    int lane = tid & 63, wv = tid >> 6;
    int v = ls;
#pragma unroll
    for (int off = 1; off < 64; off <<= 1) {
        int o = __shfl_down(v, off);
        if (lane + off < 64) v += o;
    }
    if (lane == 0) wsum[wv] = v;
    __syncthreads();
    int add = 0;
    for (int q = wv + 1; q < NW2; ++q) add += wsum[q];
    int mine = v + add;              // count in bins [lo..2047]
    int above = mine - ls;           // count in bins [lo+g..2047]
    if (above < K && mine >= K) {    // exactly one thread crosses
        int cum = above;
        for (int b = lo + g - 1; b >= lo; --b) {
            cum += hist[b];
            if (cum >= K) {
                *shPref = prefBase | ((unsigned)b << shift);
                *shK = K - (cum - hist[b]);
                break;
            }
        }
    }
    __syncthreads();
}

// --------- Fused kernel: score + sectored handshake + last-block NMS --------
// vs round 9: slist staging DROPPED (phase 2 radixes the global sector
// segments with coherent loads) and LDS aliased by live range -> ~17.6 KB
// total -> 8 blocks/CU for the bulk score phase (round-9's 37 KB capped it
// at 4 blocks/CU and throttled phase 1). Aliases (barrier-separated):
//   hist (dead after 2nd suffix_pick)  <-> sRow (written in matrix phase)
//   eqKey (dead after tie-rank)        <-> sorted (written at rank phase)
//   sel (dead after rank phase)        <-> accIdx/accBox (written by walk)
// Fallback reduce uses dedicated redBuf (NOT eqKey: that aliases sorted,
// which stays live through the epilogue).
__global__ __launch_bounds__(BT2) void k_all(Ptrs P, float* scoreAll, int* clsAll,
                                             unsigned long long* list, int* secCnt,
                                             int* dSec, int* dImg, float* out)
{
    // region A: 8192 B  = hist[2048] | sRow[256][4]
    // region B: 2048 B  = eqKey[256] | sorted[256]
    // region C: 2112 B  = sel[256] (2048) | accIdx[100](400,pad 512)+accBox[100](1600)
    __shared__ __align__(16) char pool[8192 + 2048 + 2112];
    __shared__ float4 sBox[256];                 // 4 KB
    __shared__ float  sCls[256];                 // 1 KB
    __shared__ unsigned long long redBuf[NW2];   // fallback reduce scratch
    __shared__ int wsum[NW2];
    __shared__ int cntS[SEC], offS[SEC+1];
    __shared__ unsigned int shPref;
    __shared__ int shK, tick, eqn;
    __shared__ int shNaM, shNa, shTotal, shMaxS;
    __shared__ unsigned long long shLast;
    __shared__ int lcnt, lbase, lastFlag;

    int* hist = (int*)pool;
    unsigned long long (*sRow)[4] = (unsigned long long (*)[4])pool;
    unsigned long long* eqKey  = (unsigned long long*)(pool + 8192);
    unsigned long long* sorted = (unsigned long long*)(pool + 8192);
    unsigned long long* sel    = (unsigned long long*)(pool + 10240);
    int*    accIdx = (int*)(pool + 10240);
    float4* accBox = (float4*)(pool + 10240 + 512);

    int tid = threadIdx.x;
    int img = blockIdx.y;
    int blk = blockIdx.x;            // [0,341)
    int s   = blk & 7;               // sector
    int ssz = (s < 5) ? 43 : 42;     // blocks in this sector (5*43+3*42=341)

    // ============================ PHASE 1 ===================================
    {
        int posb = tid >> 2;             // position within block [0,64)
        int l    = tid & 3;              // lane within 4-lane group
        int p    = blk*64 + posb;
        int lvl, base, lw;
        if (blk < 256)      { lvl=0; base=0;     lw=7; }
        else if (blk < 320) { lvl=1; base=16384; lw=6; }
        else if (blk < 336) { lvl=2; base=20480; lw=5; }
        else if (blk < 340) { lvl=3; base=21504; lw=4; }
        else                { lvl=4; base=21760; lw=3; }
        int pl = p - base;
        long long lidx = (long long)img*(1<<(2*lw)) + pl;

        if (tid == 0) lcnt = 0;
        __syncthreads();

        const float4* c4 = (const float4*)(P.cls[lvl] + lidx*80);
        float mx = -3.4e38f; int mi = 0;
#pragma unroll
        for (int j = 0; j < 5; ++j) {
            int k = j*4 + l;
            float4 v = c4[k];
            int cb = k*4;
            if (v.x > mx){mx=v.x; mi=cb;}
            if (v.y > mx){mx=v.y; mi=cb+1;}
            if (v.z > mx){mx=v.z; mi=cb+2;}
            if (v.w > mx){mx=v.w; mi=cb+3;}
        }
#pragma unroll
        for (int d = 1; d < 4; d <<= 1) {
            float omx = __shfl_xor(mx, d);
            int   omi = __shfl_xor(mi, d);
            if (omx > mx || (omx == mx && omi < mi)) { mx = omx; mi = omi; }
        }
        int myTicket = -1;
        unsigned long long myKey = 0;
        if (l == 0) {
            float ct = P.ctr[lvl][lidx];
            float sc = sqrtf(sigf(mx)*sigf(ct));   // sigmoid(max)==max(sigmoid)
            int o = img*NPOS + p;
            cstore_u32((unsigned*)scoreAll + o, __float_as_uint(sc));
            cstore_i32(clsAll + o, mi);
            if (sc > TFAST) {
                myTicket = atomicAdd(&lcnt, 1);
                myKey = mkkey(__float_as_uint(sc), p);
            }
        }
        __syncthreads();
        if (tid == 0)
            lbase = lcnt ? __hip_atomic_fetch_add(&secCnt[(img*SEC+s)*CSTRIDE], lcnt,
                                __ATOMIC_RELAXED, __HIP_MEMORY_SCOPE_AGENT) : 0;
        __syncthreads();
        if (myTicket >= 0) {
            int t = lbase + myTicket;
            if (t < SCAP) cstore_u64(list + (long long)img*CAP + s*SCAP + t, myKey);
        }
    }

    // ---- sectored completion handshake (chains ~43-deep) -------------------
    __syncthreads();                     // drain this block's coherent stores
    if (tid == 0) {
        lastFlag = 0;
        int t = __hip_atomic_fetch_add(&dSec[(img*SEC+s)*CSTRIDE], 1,
                                       __ATOMIC_RELAXED, __HIP_MEMORY_SCOPE_AGENT);
        if (t == ssz - 1) {              // last block of this sector
            int t2 = __hip_atomic_fetch_add(&dImg[img*CSTRIDE], 1,
                                       __ATOMIC_RELAXED, __HIP_MEMORY_SCOPE_AGENT);
            if (t2 == SEC - 1) lastFlag = 1;   // last sector of this image
        }
    }
    __syncthreads();
    if (!lastFlag) return;

    // ============================ PHASE 2 ===================================
    const unsigned int* gs = (const unsigned int*)scoreAll + (long long)img*NPOS;
    const int* gCls = clsAll + (long long)img*NPOS;
    const unsigned long long* gl = list + (long long)img*CAP;

    float* outS = out + img*100;
    float* outC = out + 800 + img*100;
    float* outB = out + 1600 + img*400;

    if (tid < SEC) cntS[tid] = cload_i32(&secCnt[(img*SEC+tid)*CSTRIDE]);
    if (tid == 0) { tick = 0; eqn = 0; }
    for (int i = tid; i < 2048; i += BT2) hist[i] = 0;
    __syncthreads();
    if (tid == 0) {
        int o = 0, mx = 0;
        for (int q = 0; q < SEC; ++q) {
            offS[q] = o;
            int c = cntS[q];
            o += c; if (c > mx) mx = c;
        }
        offS[SEC] = o; shTotal = o; shMaxS = mx;
    }
    __syncthreads();
    int total = shTotal;
    bool fastPath = (total >= 256 && shMaxS <= SCAP);

    unsigned int kth; int need;
    if (fastPath) {
        // ---- radix over global sector segments (coherent loads) ----
        for (int q = 0; q < SEC; ++q) {
            int c = cntS[q];
            const unsigned long long* seg = gl + q*SCAP;
            for (int i = tid; i < c; i += BT2)
                atomicAdd(&hist[(unsigned)(cload_u64(seg + i) >> 35)], 1);
        }
        __syncthreads();
        suffix_pick(hist, wsum, 256, 0u, 19, &shPref, &shK, tid);
        unsigned int pref = shPref; int K2 = shK;
        for (int i = tid; i < 2048; i += BT2) hist[i] = 0;
        __syncthreads();
        for (int q = 0; q < SEC; ++q) {
            int c = cntS[q];
            const unsigned long long* seg = gl + q*SCAP;
            for (int i = tid; i < c; i += BT2) {
                unsigned long long k = cload_u64(seg + i);
                if ((unsigned)(k >> 35) == (pref >> 19))
                    atomicAdd(&hist[(unsigned)(k >> 24) & 2047], 1);
            }
        }
        __syncthreads();
        suffix_pick(hist, wsum, K2, pref, 8, &shPref, &shK, tid);
        kth = shPref >> 8; need = shK;
        for (int q = 0; q < SEC; ++q) {
            int c = cntS[q];
            const unsigned long long* seg = gl + q*SCAP;
            for (int i = tid; i < c; i += BT2) {
                unsigned long long k = cload_u64(seg + i);
                unsigned int hb = (unsigned)(k >> 24);
                if (hb > kth)       { int t = atomicAdd(&tick, 1); sel[t] = k; }
                else if (hb == kth) { int t = atomicAdd(&eqn, 1); if (t < 256) eqKey[t] = k; }
            }
        }
    } else {
        // ---- exact full-scan radix over all positions (coherent reads) ----
        for (int i = tid; i < NPOS; i += BT2)
            atomicAdd(&hist[cload_u32(gs + i) >> 19], 1);
        __syncthreads();
        suffix_pick(hist, wsum, 256, 0u, 19, &shPref, &shK, tid);
        unsigned int pref = shPref; int K2 = shK;
        for (int i = tid; i < 2048; i += BT2) hist[i] = 0;
        __syncthreads();
        for (int i = tid; i < NPOS; i += BT2) {
            unsigned int b = cload_u32(gs + i);
            if ((b >> 19) == (pref >> 19)) atomicAdd(&hist[(b >> 8) & 2047], 1);
        }
        __syncthreads();
        suffix_pick(hist, wsum, K2, pref, 8, &shPref, &shK, tid);
        kth = shPref >> 8; need = shK;
        for (int i = tid; i < NPOS; i += BT2) {
            unsigned int b = cload_u32(gs + i), hb = b >> 8;
            if (hb > kth)       { int t = atomicAdd(&tick, 1); sel[t] = mkkey(b, i); }
            else if (hb == kth) { int t = atomicAdd(&eqn, 1); if (t < 256) eqKey[t] = mkkey(b, i); }
        }
    }
    __syncthreads();
    int m = eqn, nG = tick;              // nG == 256-need
    if (m <= 256) {                      // keep `need` LARGEST keys among ties
        for (int q = tid; q < m; q += BT2) {
            unsigned long long kq = eqKey[q];
            int r = 0;
            for (int j = 0; j < m; ++j) r += (eqKey[j] > kq);
            if (r < need) sel[nG + r] = kq;
        }
    } else if (tid == 0) {               // unreachable-in-practice fallback
        unsigned long long last = ~0ULL;
        for (int c = 0; c < need; ++c) {
            unsigned long long best = 0;
            if (fastPath) {
                for (int q = 0; q < SEC; ++q) {
                    int cq = cntS[q];
                    const unsigned long long* seg = gl + q*SCAP;
                    for (int i = 0; i < cq; ++i) {
                        unsigned long long k2 = cload_u64(seg + i);
                        if ((unsigned)(k2 >> 24) == kth && k2 < last && k2 > best) best = k2;
                    }
                }
            } else {
                for (int i = 0; i < NPOS; ++i) {
                    unsigned int b = cload_u32(gs + i);
                    if ((b >> 8) == kth) {
                        unsigned long long k2 = mkkey(b, i);
                        if (k2 < last && k2 > best) best = k2;
                    }
                }
            }
            sel[nG + c] = best; last = best;
        }
    }
    __syncthreads();                     // eqKey live range ENDS here

    // rank 256 unique keys by counting (sorted aliases dead eqKey)
    {
        unsigned long long k = sel[tid];
        int r = 0;
        for (int j = 0; j < 256; ++j) r += (sel[j] > k);
        sorted[r] = k;
    }
    __syncthreads();                     // sel live range ENDS here
    {
        int p = 65535 - (int)(sorted[tid] & 0xFFFF);
        sBox[tid] = computeBox(P, img, p);
        sCls[tid] = (float)cload_i32(gCls + p);
    }

    // nValid = # leading candidates with score > MINS (sorted desc, so prefix).
    float myScore = __uint_as_float((unsigned int)(sorted[tid] >> 16));
    int nValid = __syncthreads_count(myScore > MINS ? 1 : 0);

    // ---- suppression matrix: thread=row, loop over 4 quarters --------------
    // (sRow aliases dead hist; hist's last read was the 2nd suffix_pick)
    {
        float4 bi = sBox[tid];
        float  ai = (bi.z-bi.x)*(bi.w-bi.y);
#pragma unroll
        for (int qq = 0; qq < 4; ++qq) {
            unsigned long long mv = 0;
#pragma unroll 8
            for (int jj = 0; jj < 64; ++jj) {
                int j = qq*64 + jj;
                float4 bj = sBox[j];
                float aj = (bj.z-bj.x)*(bj.w-bj.y);
                float iw = fmaxf(fminf(bj.z,bi.z)-fmaxf(bj.x,bi.x),0.f);
                float ih = fmaxf(fminf(bj.w,bi.w)-fmaxf(bj.y,bi.y),0.f);
                float in_ = iw*ih;
                bool s2 = (j > tid) && (in_/(aj+ai-in_+1e-12f) > 0.6f);
                mv |= ((unsigned long long)s2) << jj;
            }
            sRow[tid][qq] = mv;
        }
    }
    __syncthreads();

    // ---- serial bitmask walk (thread 0); accIdx/accBox alias dead sel ------
    if (tid == 0) {
        int na = 0;
        unsigned long long r0=0, r1=0, r2=0, r3=0;
#define FCOS_WBLK(RW, IB)                                                  \
        {                                                                  \
            int hi = nValid < ((IB)+1)*64 ? nValid : ((IB)+1)*64;          \
            for (int i = (IB)*64; i < hi && na < 100; ++i) {               \
                if ((RW >> (i - (IB)*64)) & 1ull) continue;                \
                accIdx[na++] = i;                                          \
                const ulonglong2* rp = (const ulonglong2*)sRow[i];         \
                ulonglong2 ra = rp[0], rb = rp[1];                         \
                r0 |= ra.x; r1 |= ra.y; r2 |= rb.x; r3 |= rb.y;            \
            }                                                              \
        }
        FCOS_WBLK(r0,0) FCOS_WBLK(r1,1) FCOS_WBLK(r2,2) FCOS_WBLK(r3,3)
#undef FCOS_WBLK
        shNaM = na; shNa = na;
    }
    __syncthreads();

    // ---- fallback: top-256 exhausted before 100 accepted (never on real ----
    // data; guarded by nValid==256). Full-block scan over all positions.
    int naM = shNaM;
    if (naM < 100 && nValid == 256) {
        if (tid < naM) accBox[tid] = sBox[accIdx[tid]];
        if (tid == 0) shLast = sorted[255];
        __syncthreads();
        while (true) {
            if (shNa >= 100) break;
            unsigned long long last = shLast;
            unsigned long long bk = 0;
            for (int i = tid; i < NPOS; i += BT2) {
                unsigned long long k2 = mkkey(cload_u32(gs + i), i);
                if (k2 < last && k2 > bk) bk = k2;
            }
#pragma unroll
            for (int off = 32; off > 0; off >>= 1) {
                unsigned long long o = __shfl_down(bk, off);
                if (o > bk) bk = o;
            }
            int lane = tid & 63, wv = tid >> 6;
            if (lane == 0) redBuf[wv] = bk;
            __syncthreads();
            if (tid == 0) {
                unsigned long long best = 0;
                for (int q = 0; q < NW2; ++q) if (redBuf[q] > best) best = redBuf[q];
                shLast = best;
            }
            __syncthreads();
            unsigned long long ck = shLast;
            if (ck == 0ULL) break;
            float sc = __uint_as_float((unsigned int)(ck >> 16));
            if (!(sc > MINS)) break;
            int p = 65535 - (int)(ck & 0xFFFF);
            float4 bb = computeBox(P, img, p);
            float ba = (bb.z-bb.x)*(bb.w-bb.y);
            int na = shNa;
            bool mySup = false;
            if (tid < na) {
                float4 ab = accBox[tid];
                float aa = (ab.z-ab.x)*(ab.w-ab.y);
                float iw = fmaxf(fminf(bb.z,ab.z)-fmaxf(bb.x,ab.x),0.f);
                float ih = fmaxf(fminf(bb.w,ab.w)-fmaxf(bb.y,ab.y),0.f);
                float in_ = iw*ih;
                mySup = in_/(ba+aa-in_+1e-12f) > 0.6f;
            }
            int supCnt = __syncthreads_count(mySup);
            if (supCnt == 0) {
                if (tid == 0) {
                    int na2 = shNa;
                    outS[na2] = sc;
                    outC[na2] = (float)cload_i32(gCls + p);
                    outB[4*na2+0]=bb.x; outB[4*na2+1]=bb.y;
                    outB[4*na2+2]=bb.z; outB[4*na2+3]=bb.w;
                    accBox[na2] = bb;
                    shNa = na2 + 1;
                }
            }
            __syncthreads();
        }
    }
    __syncthreads();

    // ---- parallel epilogue: main accepts from LDS; -1 fill for the rest ----
    {
        int naM2 = shNaM, naT = shNa;
        if (tid < 100) {
            if (tid < naM2) {
                int r = accIdx[tid];
                unsigned long long k = sorted[r];
                float4 b = sBox[r];
                outS[tid] = __uint_as_float((unsigned int)(k >> 16));
                outC[tid] = sCls[r];
                outB[4*tid+0]=b.x; outB[4*tid+1]=b.y;
                outB[4*tid+2]=b.z; outB[4*tid+3]=b.w;
            } else if (tid >= naT) {     // (naM..naT) written by fallback
                outS[tid] = -1.f; outC[tid] = -1.f;
                outB[4*tid+0]=-1.f; outB[4*tid+1]=-1.f;
                outB[4*tid+2]=-1.f; outB[4*tid+3]=-1.f;
            }
        }
    }
}

extern "C" void kernel_launch(void* const* d_in, const int* in_sizes, int n_in,
                              void* d_out, int out_size, void* d_ws, size_t ws_size,
                              hipStream_t stream) {
    Ptrs P;
    bool interleaved = (in_sizes[1] == 8 * 128 * 128 * 4);
    for (int i = 0; i < 5; ++i) {
        if (interleaved) {
            P.cls[i] = (const float*)d_in[3*i];
            P.reg[i] = (const float*)d_in[3*i + 1];
            P.ctr[i] = (const float*)d_in[3*i + 2];
        } else {
            P.cls[i] = (const float*)d_in[i];
            P.reg[i] = (const float*)d_in[5 + i];
            P.ctr[i] = (const float*)d_in[10 + i];
        }
    }

    char* wbase = (char*)d_ws;
    size_t off = 0;
    auto alloc = [&](size_t bytes) -> void* {
        void* r = wbase + off;
        off += (bytes + 255) & ~(size_t)255;
        return r;
    };
    float*              scoreAll = (float*)alloc((size_t)8 * NPOS * 4);
    int*                clsAll   = (int*)alloc((size_t)8 * NPOS * 4);
    unsigned long long* list     = (unsigned long long*)alloc((size_t)8 * CAP * 8);
    int*                secCnt   = (int*)alloc((size_t)8 * SEC * CSTRIDE * 4);  // 8 KB
    int*                dSec     = (int*)alloc((size_t)8 * SEC * CSTRIDE * 4);  // 8 KB
    int*                dImg     = (int*)alloc((size_t)8 * CSTRIDE * 4);        // 1 KB

    // secCnt, dSec, dImg are contiguous 256-B-aligned allocations: one memset.
    hipMemsetAsync(secCnt, 0,
                   (size_t)(8*SEC*CSTRIDE + 8*SEC*CSTRIDE + 8*CSTRIDE) * 4, stream);

    dim3 gA(341, 8);   // 341*64 = 21824 positions, level boundaries block-aligned
    k_all<<<gA, BT2, 0, stream>>>(P, scoreAll, clsAll, list, secCnt, dSec, dImg,
                                  (float*)d_out);
}

// Round 11
// 151.799 us; speedup vs baseline: 1.1860x; 1.1860x over previous
//
#include <hip/hip_runtime.h>

#define NPOS 21824          // 16384+4096+1024+256+64 positions per image
#define NBLK 341            // score blocks per image (64 positions each)
#define MINS 0.05f
#define TFAST 0.85f         // static pre-filter threshold (fast path only)
#define SLCAP 4096          // LDS staging capacity for compact list
#define BTN  1024           // k_nms threads
#define NWN  (BTN/64)       // 16 waves

struct Ptrs { const float* cls[5]; const float* reg[5]; const float* ctr[5]; };

__device__ __forceinline__ float sigf(float x){ return 1.0f/(1.0f+expf(-x)); }

// key = (score_bits<<16) | (65535-p): desc key == desc score, ties lower p.
// Matches reference ordering (concatenation order = level-major position p;
// argmax picks first max; jax top_k keeps lower index on ties).
__device__ __forceinline__ unsigned long long mkkey(unsigned int b, int p){
    return ((unsigned long long)b << 16) | (unsigned)(65535 - p);
}

// Recompute the snapped box for position p (bit-identical to the original
// k_score path: same expression order, same expf, same casts/clamps).
__device__ __forceinline__ float4 computeBox(const Ptrs& P, int img, int p){
    int base, lw, stride, lvl;
    if (p < 16384)      { lvl=0; base=0;     lw=7; stride=8;   }
    else if (p < 20480) { lvl=1; base=16384; lw=6; stride=16;  }
    else if (p < 21504) { lvl=2; base=20480; lw=5; stride=32;  }
    else if (p < 21760) { lvl=3; base=21504; lw=4; stride=64;  }
    else                { lvl=4; base=21760; lw=3; stride=128; }
    int pl = p - base;
    int h = pl >> lw, w = pl & ((1<<lw)-1);
    long long lidx = (long long)img*(1<<(2*lw)) + pl;
    float4 rg = ((const float4*)P.reg[lvl])[lidx];
    float x = (w + 0.5f)*(float)stride;
    float y = (h + 0.5f)*(float)stride;
    int ix1 = (int)(x - expf(rg.x));
    int iy1 = (int)(y - expf(rg.y));
    int ix2 = (int)(x + expf(rg.z));
    int iy2 = (int)(y + expf(rg.w));
    ix1 = max(ix1,0); iy1 = max(iy1,0);
    ix2 = min(ix2,1023); iy2 = min(iy2,1023);
    return make_float4((float)ix1,(float)iy1,(float)ix2,(float)iy2);
}

// ---------------- Kernel A: score / class + per-block list segments --------
// ZERO global atomics (round-8 post-mortem: the 341-deep same-address
// listCnt chain was ~25-50 us inside k_score). Each block owns a fixed
// 64-slot segment of `list` and writes its count with one plain store.
// Kernel boundary provides producer->consumer coherence.
__global__ __launch_bounds__(256) void k_score(Ptrs P, float* scoreAll, int* clsAll,
                                               unsigned long long* list, int* cnt)
{
    __shared__ int lcnt;
    int img  = blockIdx.y;
    int blk  = blockIdx.x;           // [0,341)
    int tid  = threadIdx.x;
    int posb = tid >> 2;             // position within block [0,64)
    int l    = tid & 3;              // lane within 4-lane group
    int p    = blk*64 + posb;
    int lvl, base, lw;
    if (blk < 256)      { lvl=0; base=0;     lw=7; }
    else if (blk < 320) { lvl=1; base=16384; lw=6; }
    else if (blk < 336) { lvl=2; base=20480; lw=5; }
    else if (blk < 340) { lvl=3; base=21504; lw=4; }
    else                { lvl=4; base=21760; lw=3; }
    int pl = p - base;
    long long lidx = (long long)img*(1<<(2*lw)) + pl;

    if (tid == 0) lcnt = 0;
    __syncthreads();

    const float4* c4 = (const float4*)(P.cls[lvl] + lidx*80);
    float mx = -3.4e38f; int mi = 0;
#pragma unroll
    for (int j = 0; j < 5; ++j) {
        int k = j*4 + l;
        float4 v = c4[k];
        int cb = k*4;
        if (v.x > mx){mx=v.x; mi=cb;}
        if (v.y > mx){mx=v.y; mi=cb+1;}
        if (v.z > mx){mx=v.z; mi=cb+2;}
        if (v.w > mx){mx=v.w; mi=cb+3;}
    }
#pragma unroll
    for (int d = 1; d < 4; d <<= 1) {
        float omx = __shfl_xor(mx, d);
        int   omi = __shfl_xor(mi, d);
        if (omx > mx || (omx == mx && omi < mi)) { mx = omx; mi = omi; }
    }
    if (l == 0) {
        float ct = P.ctr[lvl][lidx];
        float sc = sqrtf(sigf(mx)*sigf(ct));   // sigmoid(max)==max(sigmoid)
        int o = img*NPOS + p;
        scoreAll[o] = sc;
        clsAll[o]   = mi;
        if (sc > TFAST) {                      // LDS ticket only (cheap)
            int t = atomicAdd(&lcnt, 1);       // t < 64 by construction
            list[((long long)img*NBLK + blk)*64 + t] = mkkey(__float_as_uint(sc), p);
        }
    }
    __syncthreads();
    if (tid == 0) cnt[img*NBLK + blk] = lcnt;  // plain store, unique address
}

// ---- suffix-scan pick over a 2048-bin LDS histogram (2 bins/thread) --------
__device__ void suffix_pick(const int* hist, int* wsum, int K,
                            unsigned int prefBase, int shift,
                            unsigned int* shPref, int* shK, int tid)
{
    int lo = tid*2;
    int h0 = hist[lo], h1 = hist[lo+1];
    int ls = h0 + h1;
    int lane = tid & 63, wv = tid >> 6;
    int v = ls;
#pragma unroll
    for (int off = 1; off < 64; off <<= 1) {
        int o = __shfl_down(v, off);
        if (lane + off < 64) v += o;
    }
    if (lane == 0) wsum[wv] = v;
    __syncthreads();
    int add = 0;
    for (int q = wv + 1; q < NWN; ++q) add += wsum[q];
    int mine = v + add;              // count in bins [lo..2047]
    int above = mine - ls;           // count in bins [lo+2..2047]
    if (above < K && mine >= K) {    // exactly one thread crosses
        if (above + h1 >= K) { *shPref = prefBase | ((unsigned)(lo+1) << shift); *shK = K - above; }
        else                 { *shPref = prefBase | ((unsigned)lo << shift); *shK = K - above - h1; }
    }
    __syncthreads();
}

// ------ Kernel B: gather -> LDS radix top-256 -> matrix-NMS (8 x 1024) ------
// Fast path: prefix-scan the 341 per-block counts, gather all segments into
// LDS once (single global pass), then both radix passes + selection run at
// LDS speed (round-5 re-read global 3x). total>=256 guarantees the global
// top-256 is inside the list (256th score > TFAST); total<=SLCAP bounds LDS.
// Segment overflow impossible (<=64 positions per block). Otherwise exact
// full-scan radix over scoreAll. Greedy NMS == rank-order scan with a
// 256-bit suppression mask from the parallel-built IoU>thr matrix.
__global__ __launch_bounds__(BTN) void k_nms(Ptrs P, const float* scoreAll,
                                             const int* clsAll,
                                             const unsigned long long* list,
                                             const int* cnt, float* out)
{
    __shared__ __align__(16) unsigned long long slist[SLCAP];   // 32 KB
    __shared__ int hist[2048];                                  // 8 KB
    __shared__ unsigned long long eqKey[1024];                  // 8 KB
    __shared__ unsigned long long sel[256];
    __shared__ unsigned long long sorted[256];
    __shared__ float4 sBox[256];
    __shared__ float  sCls[256];
    __shared__ __align__(16) unsigned long long sRow[256][4];   // 8 KB
    __shared__ int accIdx[100];
    __shared__ float4 accBox[100];
    __shared__ int cntL[NBLK], offL[NBLK];
    __shared__ int wsum[NWN], wsumP[NWN];
    __shared__ unsigned long long redBuf[NWN];
    __shared__ unsigned int shPref;
    __shared__ int shK, tick, eqn;
    __shared__ int shNaM, shNa, shTotal;
    __shared__ unsigned long long shLast;

    int img = blockIdx.x, tid = threadIdx.x;
    const unsigned int* gs = (const unsigned int*)scoreAll + (long long)img*NPOS;
    const int* gCls = clsAll + (long long)img*NPOS;
    const unsigned long long* gl = list + (long long)img*NBLK*64;

    float* outS = out + img*100;
    float* outC = out + 800 + img*100;
    float* outB = out + 1600 + img*400;

    // ---- load counts + block-wide prefix scan (offsets, total) -------------
    if (tid < NBLK) cntL[tid] = cnt[img*NBLK + tid];
    if (tid == 0) { tick = 0; eqn = 0; }
    for (int i = tid; i < 2048; i += BTN) hist[i] = 0;
    __syncthreads();
    {
        int lane = tid & 63, wv = tid >> 6;
        int e = (tid < NBLK) ? cntL[tid] : 0;
        int v = e;
#pragma unroll
        for (int off = 1; off < 64; off <<= 1) {
            int o = __shfl_up(v, off);
            if (lane >= off) v += o;
        }
        if (lane == 63) wsumP[wv] = v;
        __syncthreads();
        if (wv == 0) {
            int s = (lane < NWN) ? wsumP[lane] : 0;
            int v2 = s;
#pragma unroll
            for (int off = 1; off < NWN; off <<= 1) {
                int o = __shfl_up(v2, off);
                if (lane >= off) v2 += o;
            }
            if (lane < NWN) wsumP[lane] = v2;   // inclusive wave sums
        }
        __syncthreads();
        int basev = (wv > 0) ? wsumP[wv-1] : 0;
        int incl = v + basev;
        if (tid < NBLK) offL[tid] = incl - e;   // exclusive offset
        if (tid == NBLK-1) shTotal = incl;
        __syncthreads();
    }
    int total = shTotal;
    bool fastPath = (total >= 256 && total <= SLCAP);

    // ---- gather segments into LDS (one global pass, loads pipeline) --------
    if (fastPath && tid < NBLK) {
        int c = cntL[tid], o = offL[tid];
        const unsigned long long* seg = gl + tid*64;
        for (int j = 0; j < c; ++j) slist[o + j] = seg[j];
    }
    __syncthreads();

    unsigned int kth; int need;
    if (fastPath) {
        // ---- 2-pass radix over LDS-staged list (key>>35 = score>>19) ----
        for (int i = tid; i < total; i += BTN)
            atomicAdd(&hist[(unsigned)(slist[i] >> 35)], 1);
        __syncthreads();
        suffix_pick(hist, wsum, 256, 0u, 19, &shPref, &shK, tid);
        unsigned int pref = shPref; int K2 = shK;
        for (int i = tid; i < 2048; i += BTN) hist[i] = 0;
        __syncthreads();
        for (int i = tid; i < total; i += BTN) {
            unsigned long long k = slist[i];
            if ((unsigned)(k >> 35) == (pref >> 19))
                atomicAdd(&hist[(unsigned)(k >> 24) & 2047], 1);
        }
        __syncthreads();
        suffix_pick(hist, wsum, K2, pref, 8, &shPref, &shK, tid);
        kth = shPref >> 8; need = shK;
        for (int i = tid; i < total; i += BTN) {
            unsigned long long k = slist[i];
            unsigned int hb = (unsigned)(k >> 24);
            if (hb > kth)       { int t = atomicAdd(&tick, 1); sel[t] = k; }
            else if (hb == kth) { int t = atomicAdd(&eqn, 1); if (t < 1024) eqKey[t] = k; }
        }
    } else {
        // ---- exact full-scan radix over all positions ----
#pragma unroll 4
        for (int i = tid; i < NPOS; i += BTN)
            atomicAdd(&hist[gs[i] >> 19], 1);
        __syncthreads();
        suffix_pick(hist, wsum, 256, 0u, 19, &shPref, &shK, tid);
        unsigned int pref = shPref; int K2 = shK;
        for (int i = tid; i < 2048; i += BTN) hist[i] = 0;
        __syncthreads();
#pragma unroll 4
        for (int i = tid; i < NPOS; i += BTN) {
            unsigned int b = gs[i];
            if ((b >> 19) == (pref >> 19)) atomicAdd(&hist[(b >> 8) & 2047], 1);
        }
        __syncthreads();
        suffix_pick(hist, wsum, K2, pref, 8, &shPref, &shK, tid);
        kth = shPref >> 8; need = shK;
#pragma unroll 4
        for (int i = tid; i < NPOS; i += BTN) {
            unsigned int b = gs[i], hb = b >> 8;
            if (hb > kth)       { int t = atomicAdd(&tick, 1); sel[t] = mkkey(b, i); }
            else if (hb == kth) { int t = atomicAdd(&eqn, 1); if (t < 1024) eqKey[t] = mkkey(b, i); }
        }
    }
    __syncthreads();
    int m = eqn, nG = tick;              // nG == 256-need
    if (m <= 1024) {                     // keep `need` LARGEST keys among ties
        for (int q = tid; q < m; q += BTN) {
            unsigned long long kq = eqKey[q];
            int r = 0;
            for (int j = 0; j < m; ++j) r += (eqKey[j] > kq);
            if (r < need) sel[nG + r] = kq;
        }
    } else if (tid == 0) {               // unreachable-in-practice fallback
        unsigned long long last = ~0ULL;
        for (int c = 0; c < need; ++c) {
            unsigned long long best = 0;
            if (fastPath) {
                for (int i = 0; i < total; ++i) {
                    unsigned long long k2 = slist[i];
                    if ((unsigned)(k2 >> 24) == kth && k2 < last && k2 > best) best = k2;
                }
            } else {
                for (int i = 0; i < NPOS; ++i) {
                    unsigned int b = gs[i];
                    if ((b >> 8) == kth) {
                        unsigned long long k2 = mkkey(b, i);
                        if (k2 < last && k2 > best) best = k2;
                    }
                }
            }
            sel[nG + c] = best; last = best;
        }
    }
    __syncthreads();

    // rank 256 unique keys by counting (1 key/thread, broadcast LDS reads)
    if (tid < 256) {
        unsigned long long k = sel[tid];
        int r = 0;
        for (int j = 0; j < 256; ++j) r += (sel[j] > k);
        sorted[r] = k;
    }
    __syncthreads();
    if (tid < 256) {
        int p = 65535 - (int)(sorted[tid] & 0xFFFF);
        sBox[tid] = computeBox(P, img, p);
        sCls[tid] = (float)gCls[p];
    }

    // nValid = # leading candidates with score > MINS (sorted desc, so prefix).
    // __syncthreads_count doubles as the barrier covering sBox/sCls writes.
    float myScore = 0.f;
    if (tid < 256) myScore = __uint_as_float((unsigned int)(sorted[tid] >> 16));
    int nValid = __syncthreads_count(myScore > MINS ? 1 : 0);

    // ---- suppression matrix: thread (row,quarter) builds 64 bits of row ----
    // Float arithmetic order matches serial greedy NMS exactly:
    // den = area(candidate j) + area(accepted i) - inter + 1e-12.
    {
        int row = tid & 255, qq = tid >> 8;
        float4 bi = sBox[row];
        float  ai = (bi.z-bi.x)*(bi.w-bi.y);
        unsigned long long mv = 0;
#pragma unroll 8
        for (int jj = 0; jj < 64; ++jj) {
            int j = qq*64 + jj;
            float4 bj = sBox[j];
            float aj = (bj.z-bj.x)*(bj.w-bj.y);
            float iw = fmaxf(fminf(bj.z,bi.z)-fmaxf(bj.x,bi.x),0.f);
            float ih = fmaxf(fminf(bj.w,bi.w)-fmaxf(bj.y,bi.y),0.f);
            float in_ = iw*ih;
            bool s = (j > row) && (in_/(aj+ai-in_+1e-12f) > 0.6f);
            mv |= ((unsigned long long)s) << jj;
        }
        sRow[row][qq] = mv;
    }
    __syncthreads();

    // ---- serial bitmask walk (thread 0): ~5cy/suppressed, ~130cy/accept ----
    if (tid == 0) {
        int na = 0;
        unsigned long long r0=0, r1=0, r2=0, r3=0;
#define FCOS_WBLK(RW, IB)                                                  \
        {                                                                  \
            int hi = nValid < ((IB)+1)*64 ? nValid : ((IB)+1)*64;          \
            for (int i = (IB)*64; i < hi && na < 100; ++i) {               \
                if ((RW >> (i - (IB)*64)) & 1ull) continue;                \
                accIdx[na++] = i;                                          \
                const ulonglong2* rp = (const ulonglong2*)sRow[i];         \
                ulonglong2 ra = rp[0], rb = rp[1];                         \
                r0 |= ra.x; r1 |= ra.y; r2 |= rb.x; r3 |= rb.y;            \
            }                                                              \
        }
        FCOS_WBLK(r0,0) FCOS_WBLK(r1,1) FCOS_WBLK(r2,2) FCOS_WBLK(r3,3)
#undef FCOS_WBLK
        shNaM = na; shNa = na;
    }
    __syncthreads();

    // ---- fallback: top-256 exhausted before 100 accepted (never on real ----
    // data; guarded by nValid==256 since keys below rank 256 have score <=
    // sorted[255]'s). Full-block scan over all positions per step.
    int naM = shNaM;
    if (naM < 100 && nValid == 256) {
        if (tid < naM) accBox[tid] = sBox[accIdx[tid]];
        if (tid == 0) shLast = sorted[255];
        __syncthreads();
        while (true) {
            if (shNa >= 100) break;
            unsigned long long last = shLast;
            unsigned long long bk = 0;
            for (int i = tid; i < NPOS; i += BTN) {
                unsigned long long k2 = mkkey(gs[i], i);
                if (k2 < last && k2 > bk) bk = k2;
            }
#pragma unroll
            for (int off = 32; off > 0; off >>= 1) {
                unsigned long long o = __shfl_down(bk, off);
                if (o > bk) bk = o;
            }
            int lane = tid & 63, wv = tid >> 6;
            if (lane == 0) redBuf[wv] = bk;
            __syncthreads();
            if (tid == 0) {
                unsigned long long best = 0;
                for (int q = 0; q < NWN; ++q) if (redBuf[q] > best) best = redBuf[q];
                shLast = best;
            }
            __syncthreads();
            unsigned long long ck = shLast;
            if (ck == 0ULL) break;
            float sc = __uint_as_float((unsigned int)(ck >> 16));
            if (!(sc > MINS)) break;
            int p = 65535 - (int)(ck & 0xFFFF);
            float4 bb = computeBox(P, img, p);
            float ba = (bb.z-bb.x)*(bb.w-bb.y);
            int na = shNa;
            bool mySup = false;
            if (tid < na) {
                float4 ab = accBox[tid];
                float aa = (ab.z-ab.x)*(ab.w-ab.y);
                float iw = fmaxf(fminf(bb.z,ab.z)-fmaxf(bb.x,ab.x),0.f);
                float ih = fmaxf(fminf(bb.w,ab.w)-fmaxf(bb.y,ab.y),0.f);
                float in_ = iw*ih;
                mySup = in_/(ba+aa-in_+1e-12f) > 0.6f;
            }
            int supCnt = __syncthreads_count(mySup);
            if (supCnt == 0) {
                if (tid == 0) {
                    int na2 = shNa;
                    outS[na2] = sc;
                    outC[na2] = (float)gCls[p];
                    outB[4*na2+0]=bb.x; outB[4*na2+1]=bb.y;
                    outB[4*na2+2]=bb.z; outB[4*na2+3]=bb.w;
                    accBox[na2] = bb;
                    shNa = na2 + 1;
                }
            }
            __syncthreads();
        }
    }
    __syncthreads();

    // ---- parallel epilogue: main accepts from LDS; -1 fill for the rest ----
    {
        int naM2 = shNaM, naT = shNa;
        if (tid < 100) {
            if (tid < naM2) {
                int r = accIdx[tid];
                unsigned long long k = sorted[r];
                float4 b = sBox[r];
                outS[tid] = __uint_as_float((unsigned int)(k >> 16));
                outC[tid] = sCls[r];
                outB[4*tid+0]=b.x; outB[4*tid+1]=b.y;
                outB[4*tid+2]=b.z; outB[4*tid+3]=b.w;
            } else if (tid >= naT) {     // (naM..naT) written by fallback
                outS[tid] = -1.f; outC[tid] = -1.f;
                outB[4*tid+0]=-1.f; outB[4*tid+1]=-1.f;
                outB[4*tid+2]=-1.f; outB[4*tid+3]=-1.f;
            }
        }
    }
}

extern "C" void kernel_launch(void* const* d_in, const int* in_sizes, int n_in,
                              void* d_out, int out_size, void* d_ws, size_t ws_size,
                              hipStream_t stream) {
    Ptrs P;
    bool interleaved = (in_sizes[1] == 8 * 128 * 128 * 4);
    for (int i = 0; i < 5; ++i) {
        if (interleaved) {
            P.cls[i] = (const float*)d_in[3*i];
            P.reg[i] = (const float*)d_in[3*i + 1];
            P.ctr[i] = (const float*)d_in[3*i + 2];
        } else {
            P.cls[i] = (const float*)d_in[i];
            P.reg[i] = (const float*)d_in[5 + i];
            P.ctr[i] = (const float*)d_in[10 + i];
        }
    }

    char* wbase = (char*)d_ws;
    size_t off = 0;
    auto alloc = [&](size_t bytes) -> void* {
        void* r = wbase + off;
        off += (bytes + 255) & ~(size_t)255;
        return r;
    };
    float*              scoreAll = (float*)alloc((size_t)8 * NPOS * 4);
    int*                clsAll   = (int*)alloc((size_t)8 * NPOS * 4);
    unsigned long long* list     = (unsigned long long*)alloc((size_t)8 * NBLK * 64 * 8);
    int*                cnt      = (int*)alloc((size_t)8 * NBLK * 4);

    // No memset needed: every cnt slot is written unconditionally by its
    // block; list slots >= cnt are never read.

    dim3 gA(NBLK, 8);  // 341*64 = 21824 positions, level boundaries block-aligned
    k_score<<<gA, 256, 0, stream>>>(P, scoreAll, clsAll, list, cnt);
    k_nms  <<<8, BTN, 0, stream>>>(P, scoreAll, clsAll, list, cnt, (float*)d_out);
}